// Round 1
// baseline (701.034 us; speedup 1.0000x reference)
//
#include <hip/hip_runtime.h>
#include <hip/hip_bf16.h>

// ---------------------------------------------------------------------------
// GCN-align highway:
//   xw = X @ w2                      (dense GEMM, f32 vector)
//   a  = relu(A @ w1); b = relu(A @ xw)   (fused dual CSR spmm)
//   T  = sigmoid(b @ wg); y = T*a + (1-T)*b   (fused into spmm epilogue)
//   out = A @ y                      (CSR spmm)
// CSR is rebuilt from COO every call (deterministic structure; within-row
// order from atomic scatter varies only at FP-rounding level).
// ---------------------------------------------------------------------------

#define GR 64  // rows per GEMM block

// ---------------- histogram ----------------
__global__ void k_hist(const int* __restrict__ rows, int* __restrict__ cnt, int nnz) {
  int e = blockIdx.x * blockDim.x + threadIdx.x;
  if (e < nnz) atomicAdd(&cnt[rows[e]], 1);
}

// ---------------- block-wide inclusive scan helper (blockDim = 1024) -------
__device__ __forceinline__ int block_incl_scan(int v, int* wsum) {
  int tid = threadIdx.x, lane = tid & 63, wid = tid >> 6;
  int incl = v;
#pragma unroll
  for (int off = 1; off < 64; off <<= 1) {
    int t = __shfl_up(incl, off);
    if (lane >= off) incl += t;
  }
  if (lane == 63) wsum[wid] = incl;
  __syncthreads();
  if (wid == 0) {
    int nw = (int)(blockDim.x >> 6);
    int wv = (lane < nw) ? wsum[lane] : 0;
    int wi = wv;
#pragma unroll
    for (int off = 1; off < 16; off <<= 1) {
      int t = __shfl_up(wi, off);
      if (lane >= off) wi += t;
    }
    if (lane < nw) wsum[lane] = wi - wv;  // exclusive wave offsets
  }
  __syncthreads();
  return incl + wsum[wid];
}

__global__ __launch_bounds__(1024) void k_scan_local(const int* __restrict__ cnt,
                                                     int* __restrict__ rp,
                                                     int* __restrict__ bsum, int n) {
  __shared__ int wsum[16];
  int gid = blockIdx.x * 1024 + threadIdx.x;
  int v = (gid < n) ? cnt[gid] : 0;
  int incl = block_incl_scan(v, wsum);
  if (gid < n) rp[gid] = incl - v;          // block-local exclusive
  if (threadIdx.x == 1023) bsum[blockIdx.x] = incl;
}

__global__ __launch_bounds__(1024) void k_scan_bsums(int* __restrict__ bsum,
                                                     int* __restrict__ boff,
                                                     int nb, int* __restrict__ rp, int n) {
  __shared__ int wsum[16];
  int tid = threadIdx.x;
  int v = (tid < nb) ? bsum[tid] : 0;
  int incl = block_incl_scan(v, wsum);
  if (tid < nb) boff[tid] = incl - v;       // exclusive block offsets
  if (tid == nb - 1) rp[n] = incl;          // total == NNZ
}

__global__ __launch_bounds__(1024) void k_scan_add(int* __restrict__ rp,
                                                   const int* __restrict__ boff, int n) {
  int gid = blockIdx.x * 1024 + threadIdx.x;
  if (gid < n) rp[gid] += boff[blockIdx.x];
}

// ---------------- COO -> CSR scatter ----------------
__global__ void k_scatter(const int* __restrict__ rows, const int* __restrict__ cols,
                          const float* __restrict__ vals, const int* __restrict__ rp,
                          int* __restrict__ fill, int* __restrict__ ccol,
                          float* __restrict__ cval, int nnz) {
  int e = blockIdx.x * blockDim.x + threadIdx.x;
  if (e >= nnz) return;
  int r = rows[e];
  int p = rp[r] + atomicAdd(&fill[r], 1);
  ccol[p] = cols[e];
  cval[p] = vals[e];
}

// ---------------- dense GEMM: XW = X @ W  (X: n x 128, W: 128 x 128) -------
__global__ __launch_bounds__(256) void k_gemm(const float* __restrict__ X,
                                              const float* __restrict__ W,
                                              float* __restrict__ XW, int n) {
  __shared__ float ws[128 * 128];  // 64 KB: whole w2, [k][j]
  __shared__ float xs[GR * 128];   // 32 KB
  int tid = threadIdx.x;
  long row0 = (long)blockIdx.x * GR;
#pragma unroll
  for (int i = tid * 4; i < 128 * 128; i += 256 * 4)
    *(float4*)&ws[i] = *(const float4*)&W[i];
  for (int i = tid; i < GR * 32; i += 256) {
    int r = i >> 5, c = (i & 31) << 2;
    long rr = row0 + r;
    if (rr >= n) rr = n - 1;
    *(float4*)&xs[r * 128 + c] = *(const float4*)&X[rr * 128 + c];
  }
  __syncthreads();
  int cg = tid & 15, rg = tid >> 4;  // 16 col-groups x 16 row-groups
  int c0 = cg * 8;
  float acc[4][8];
#pragma unroll
  for (int i = 0; i < 4; ++i)
#pragma unroll
    for (int j = 0; j < 8; ++j) acc[i][j] = 0.f;

  for (int k = 0; k < 128; k += 4) {
    float4 xv[4];
#pragma unroll
    for (int i = 0; i < 4; ++i) xv[i] = *(float4*)&xs[(rg * 4 + i) * 128 + k];
#pragma unroll
    for (int kk = 0; kk < 4; ++kk) {
      float4 wa = *(float4*)&ws[(k + kk) * 128 + c0];
      float4 wb = *(float4*)&ws[(k + kk) * 128 + c0 + 4];
#pragma unroll
      for (int i = 0; i < 4; ++i) {
        float x = ((const float*)&xv[i])[kk];
        acc[i][0] = fmaf(x, wa.x, acc[i][0]);
        acc[i][1] = fmaf(x, wa.y, acc[i][1]);
        acc[i][2] = fmaf(x, wa.z, acc[i][2]);
        acc[i][3] = fmaf(x, wa.w, acc[i][3]);
        acc[i][4] = fmaf(x, wb.x, acc[i][4]);
        acc[i][5] = fmaf(x, wb.y, acc[i][5]);
        acc[i][6] = fmaf(x, wb.z, acc[i][6]);
        acc[i][7] = fmaf(x, wb.w, acc[i][7]);
      }
    }
  }
#pragma unroll
  for (int i = 0; i < 4; ++i) {
    long r = row0 + rg * 4 + i;
    if (r < n) {
      float4 o0 = {acc[i][0], acc[i][1], acc[i][2], acc[i][3]};
      float4 o1 = {acc[i][4], acc[i][5], acc[i][6], acc[i][7]};
      *(float4*)&XW[r * 128 + c0] = o0;
      *(float4*)&XW[r * 128 + c0 + 4] = o1;
    }
  }
}

// ---------------- fused dual spmm + relu + highway gate --------------------
// one wave per row; lane holds 2 of the 128 features
__global__ __launch_bounds__(256) void k_spmm_ab(const int* __restrict__ rp,
                                                 const int* __restrict__ ccol,
                                                 const float* __restrict__ cval,
                                                 const float* __restrict__ w1,
                                                 const float* __restrict__ xw,
                                                 const float* __restrict__ wg,
                                                 float* __restrict__ y, int n) {
  int row = (int)((blockIdx.x * blockDim.x + threadIdx.x) >> 6);
  int lane = threadIdx.x & 63;
  if (row >= n) return;
  int s = rp[row], e = rp[row + 1];
  int base = lane * 2;
  float a0 = 0.f, a1 = 0.f, b0 = 0.f, b1 = 0.f;
  for (int i = s; i < e; ++i) {
    int c = ccol[i];
    float v = cval[i];
    const float2 wv = *(const float2*)(w1 + c * 128 + base);
    const float2 xv = *(const float2*)(xw + c * 128 + base);
    a0 = fmaf(v, wv.x, a0);
    a1 = fmaf(v, wv.y, a1);
    b0 = fmaf(v, xv.x, b0);
    b1 = fmaf(v, xv.y, b1);
  }
  a0 = fmaxf(a0, 0.f); a1 = fmaxf(a1, 0.f);
  b0 = fmaxf(b0, 0.f); b1 = fmaxf(b1, 0.f);
  // T = sigmoid(dot(b, wg)) -- wave-wide reduce
  float2 wgv = *(const float2*)(wg + base);
  float part = b0 * wgv.x + b1 * wgv.y;
#pragma unroll
  for (int off = 32; off > 0; off >>= 1) part += __shfl_xor(part, off);
  float T = 1.f / (1.f + __expf(-part));
  float2 yv = {T * a0 + (1.f - T) * b0, T * a1 + (1.f - T) * b1};
  *(float2*)(y + (size_t)row * 128 + base) = yv;
}

// ---------------- final spmm: out = A @ y ----------------------------------
__global__ __launch_bounds__(256) void k_spmm_out(const int* __restrict__ rp,
                                                  const int* __restrict__ ccol,
                                                  const float* __restrict__ cval,
                                                  const float* __restrict__ y,
                                                  float* __restrict__ out, int n) {
  int row = (int)((blockIdx.x * blockDim.x + threadIdx.x) >> 6);
  int lane = threadIdx.x & 63;
  if (row >= n) return;
  int s = rp[row], e = rp[row + 1];
  int base = lane * 2;
  float o0 = 0.f, o1 = 0.f;
  for (int i = s; i < e; ++i) {
    int c = ccol[i];
    float v = cval[i];
    const float2 yv = *(const float2*)(y + c * 128 + base);
    o0 = fmaf(v, yv.x, o0);
    o1 = fmaf(v, yv.y, o1);
  }
  float2 ov = {o0, o1};
  *(float2*)(out + (size_t)row * 128 + base) = ov;
}

// ---------------------------------------------------------------------------
extern "C" void kernel_launch(void* const* d_in, const int* in_sizes, int n_in,
                              void* d_out, int out_size, void* d_ws, size_t ws_size,
                              hipStream_t stream) {
  const float* X  = (const float*)d_in[0];
  const float* w1 = (const float*)d_in[1];
  const float* w2 = (const float*)d_in[2];
  const float* wg = (const float*)d_in[3];
  const float* Av = (const float*)d_in[4];
  const int*   Ar = (const int*)d_in[5];
  const int*   Ac = (const int*)d_in[6];
  float* out = (float*)d_out;
  int N   = in_sizes[0] / 128;
  int NNZ = in_sizes[4];

  char* p = (char*)d_ws;
  auto alloc = [&](size_t b) {
    char* r = p;
    p += (b + 255) & ~(size_t)255;
    return r;
  };
  int*   rp   = (int*)alloc((size_t)(N + 1) * 4);
  int*   cnt  = (int*)alloc((size_t)N * 4);
  int*   fill = (int*)alloc((size_t)N * 4);
  int*   bsum = (int*)alloc(4096);
  int*   boff = (int*)alloc(4096);
  int*   ccol = (int*)alloc((size_t)NNZ * 4);
  float* cval = (float*)alloc((size_t)NNZ * 4);
  float* xw   = (float*)alloc((size_t)N * 128 * 4);
  float* y    = (float*)alloc((size_t)N * 128 * 4);

  hipMemsetAsync(cnt, 0, (size_t)N * 4, stream);
  hipMemsetAsync(fill, 0, (size_t)N * 4, stream);

  int eb = (NNZ + 255) / 256;
  int sb = (N + 1023) / 1024;
  k_hist<<<eb, 256, 0, stream>>>(Ar, cnt, NNZ);
  k_scan_local<<<sb, 1024, 0, stream>>>(cnt, rp, bsum, N);
  k_scan_bsums<<<1, 1024, 0, stream>>>(bsum, boff, sb, rp, N);
  k_scan_add<<<sb, 1024, 0, stream>>>(rp, boff, N);
  k_scatter<<<eb, 256, 0, stream>>>(Ar, Ac, Av, rp, fill, ccol, cval, NNZ);
  k_gemm<<<(N + GR - 1) / GR, 256, 0, stream>>>(X, w2, xw, N);
  int wb = (N + 3) / 4;  // one 64-lane wave per row, 4 rows per 256-thread block
  k_spmm_ab<<<wb, 256, 0, stream>>>(rp, ccol, cval, w1, xw, wg, y, N);
  k_spmm_out<<<wb, 256, 0, stream>>>(rp, ccol, cval, y, out, N);
}

// Round 2
// 598.060 us; speedup vs baseline: 1.1722x; 1.1722x over previous
//
#include <hip/hip_runtime.h>
#include <hip/hip_bf16.h>

// ---------------------------------------------------------------------------
// GCN-align highway:
//   xw = X @ w2                           (dense GEMM, f32 vector)
//   a  = relu(A @ w1); b = relu(A @ xw)   (fused dual CSR spmm, half-wave split)
//   T  = sigmoid(b @ wg); y = T*a + (1-T)*b  (fused into spmm epilogue)
//   out = A @ y                           (CSR spmm, half-wave edge-parallel)
// CSR rebuilt from COO every call; metadata packed as int2{col, val}.
// ---------------------------------------------------------------------------

#define GR 64  // rows per GEMM block

// ---------------- histogram ----------------
__global__ void k_hist(const int* __restrict__ rows, int* __restrict__ cnt, int nnz) {
  int e = blockIdx.x * blockDim.x + threadIdx.x;
  if (e < nnz) atomicAdd(&cnt[rows[e]], 1);
}

// ---------------- block-wide inclusive scan helper (blockDim = 1024) -------
__device__ __forceinline__ int block_incl_scan(int v, int* wsum) {
  int tid = threadIdx.x, lane = tid & 63, wid = tid >> 6;
  int incl = v;
#pragma unroll
  for (int off = 1; off < 64; off <<= 1) {
    int t = __shfl_up(incl, off);
    if (lane >= off) incl += t;
  }
  if (lane == 63) wsum[wid] = incl;
  __syncthreads();
  if (wid == 0) {
    int nw = (int)(blockDim.x >> 6);
    int wv = (lane < nw) ? wsum[lane] : 0;
    int wi = wv;
#pragma unroll
    for (int off = 1; off < 16; off <<= 1) {
      int t = __shfl_up(wi, off);
      if (lane >= off) wi += t;
    }
    if (lane < nw) wsum[lane] = wi - wv;  // exclusive wave offsets
  }
  __syncthreads();
  return incl + wsum[wid];
}

__global__ __launch_bounds__(1024) void k_scan_local(const int* __restrict__ cnt,
                                                     int* __restrict__ rp,
                                                     int* __restrict__ bsum, int n) {
  __shared__ int wsum[16];
  int gid = blockIdx.x * 1024 + threadIdx.x;
  int v = (gid < n) ? cnt[gid] : 0;
  int incl = block_incl_scan(v, wsum);
  if (gid < n) rp[gid] = incl - v;          // block-local exclusive
  if (threadIdx.x == 1023) bsum[blockIdx.x] = incl;
}

__global__ __launch_bounds__(1024) void k_scan_bsums(int* __restrict__ bsum,
                                                     int* __restrict__ boff,
                                                     int nb, int* __restrict__ rp, int n) {
  __shared__ int wsum[16];
  int tid = threadIdx.x;
  int v = (tid < nb) ? bsum[tid] : 0;
  int incl = block_incl_scan(v, wsum);
  if (tid < nb) boff[tid] = incl - v;       // exclusive block offsets
  if (tid == nb - 1) rp[n] = incl;          // total == NNZ
}

__global__ __launch_bounds__(1024) void k_scan_add(int* __restrict__ rp,
                                                   const int* __restrict__ boff, int n) {
  int gid = blockIdx.x * 1024 + threadIdx.x;
  if (gid < n) rp[gid] += boff[blockIdx.x];
}

// ---------------- COO -> CSR scatter (packed {col,val} records) ------------
__global__ void k_scatter(const int* __restrict__ rows, const int* __restrict__ cols,
                          const float* __restrict__ vals, const int* __restrict__ rp,
                          int* __restrict__ fill, int2* __restrict__ ccv, int nnz) {
  int e = blockIdx.x * blockDim.x + threadIdx.x;
  if (e >= nnz) return;
  int r = rows[e];
  int p = rp[r] + atomicAdd(&fill[r], 1);
  int2 rec;
  rec.x = cols[e];
  rec.y = __float_as_int(vals[e]);
  ccv[p] = rec;
}

// ---------------- dense GEMM: XW = X @ W  (X: n x 128, W: 128 x 128) -------
__global__ __launch_bounds__(256) void k_gemm(const float* __restrict__ X,
                                              const float* __restrict__ W,
                                              float* __restrict__ XW, int n) {
  __shared__ float ws[128 * 128];  // 64 KB: whole w2, [k][j]
  __shared__ float xs[GR * 128];   // 32 KB
  int tid = threadIdx.x;
  long row0 = (long)blockIdx.x * GR;
#pragma unroll
  for (int i = tid * 4; i < 128 * 128; i += 256 * 4)
    *(float4*)&ws[i] = *(const float4*)&W[i];
  for (int i = tid; i < GR * 32; i += 256) {
    int r = i >> 5, c = (i & 31) << 2;
    long rr = row0 + r;
    if (rr >= n) rr = n - 1;
    *(float4*)&xs[r * 128 + c] = *(const float4*)&X[rr * 128 + c];
  }
  __syncthreads();
  int cg = tid & 15, rg = tid >> 4;  // 16 col-groups x 16 row-groups
  int c0 = cg * 8;
  float acc[4][8];
#pragma unroll
  for (int i = 0; i < 4; ++i)
#pragma unroll
    for (int j = 0; j < 8; ++j) acc[i][j] = 0.f;

  for (int k = 0; k < 128; k += 4) {
    float4 xv[4];
#pragma unroll
    for (int i = 0; i < 4; ++i) xv[i] = *(float4*)&xs[(rg * 4 + i) * 128 + k];
#pragma unroll
    for (int kk = 0; kk < 4; ++kk) {
      float4 wa = *(float4*)&ws[(k + kk) * 128 + c0];
      float4 wb = *(float4*)&ws[(k + kk) * 128 + c0 + 4];
#pragma unroll
      for (int i = 0; i < 4; ++i) {
        float x = ((const float*)&xv[i])[kk];
        acc[i][0] = fmaf(x, wa.x, acc[i][0]);
        acc[i][1] = fmaf(x, wa.y, acc[i][1]);
        acc[i][2] = fmaf(x, wa.z, acc[i][2]);
        acc[i][3] = fmaf(x, wa.w, acc[i][3]);
        acc[i][4] = fmaf(x, wb.x, acc[i][4]);
        acc[i][5] = fmaf(x, wb.y, acc[i][5]);
        acc[i][6] = fmaf(x, wb.z, acc[i][6]);
        acc[i][7] = fmaf(x, wb.w, acc[i][7]);
      }
    }
  }
#pragma unroll
  for (int i = 0; i < 4; ++i) {
    long r = row0 + rg * 4 + i;
    if (r < n) {
      float4 o0 = {acc[i][0], acc[i][1], acc[i][2], acc[i][3]};
      float4 o1 = {acc[i][4], acc[i][5], acc[i][6], acc[i][7]};
      *(float4*)&XW[r * 128 + c0] = o0;
      *(float4*)&XW[r * 128 + c0 + 4] = o1;
    }
  }
}

// ---------------- fused dual spmm + relu + highway gate --------------------
// one wave per row. Half-wave dual-matrix gather: lanes 0-31 fetch w1 row
// (float4 each -> 512B), lanes 32-63 fetch xw row. One load instr per edge.
__global__ __launch_bounds__(256) void k_spmm_ab(const int* __restrict__ rp,
                                                 const int2* __restrict__ ccv,
                                                 const float* __restrict__ w1,
                                                 const float* __restrict__ xw,
                                                 const float* __restrict__ wg,
                                                 float* __restrict__ y, int n) {
  int row = (int)((blockIdx.x * blockDim.x + threadIdx.x) >> 6);
  int lane = threadIdx.x & 63;
  if (row >= n) return;
  int s = rp[row], e = rp[row + 1];
  int sub = lane & 31;
  const float* src = (lane < 32) ? w1 : xw;  // per-half base
  src += sub * 4;
  float4 acc = {0.f, 0.f, 0.f, 0.f};

  int i = s;
  for (; i + 3 < e; i += 4) {
    int2 m0 = ccv[i], m1 = ccv[i + 1], m2 = ccv[i + 2], m3 = ccv[i + 3];
    float4 g0 = *(const float4*)(src + (size_t)m0.x * 128);
    float4 g1 = *(const float4*)(src + (size_t)m1.x * 128);
    float4 g2 = *(const float4*)(src + (size_t)m2.x * 128);
    float4 g3 = *(const float4*)(src + (size_t)m3.x * 128);
    float v0 = __int_as_float(m0.y), v1 = __int_as_float(m1.y);
    float v2 = __int_as_float(m2.y), v3 = __int_as_float(m3.y);
    acc.x = fmaf(v0, g0.x, acc.x); acc.y = fmaf(v0, g0.y, acc.y);
    acc.z = fmaf(v0, g0.z, acc.z); acc.w = fmaf(v0, g0.w, acc.w);
    acc.x = fmaf(v1, g1.x, acc.x); acc.y = fmaf(v1, g1.y, acc.y);
    acc.z = fmaf(v1, g1.z, acc.z); acc.w = fmaf(v1, g1.w, acc.w);
    acc.x = fmaf(v2, g2.x, acc.x); acc.y = fmaf(v2, g2.y, acc.y);
    acc.z = fmaf(v2, g2.z, acc.z); acc.w = fmaf(v2, g2.w, acc.w);
    acc.x = fmaf(v3, g3.x, acc.x); acc.y = fmaf(v3, g3.y, acc.y);
    acc.z = fmaf(v3, g3.z, acc.z); acc.w = fmaf(v3, g3.w, acc.w);
  }
  for (; i < e; ++i) {
    int2 m = ccv[i];
    float4 g = *(const float4*)(src + (size_t)m.x * 128);
    float v = __int_as_float(m.y);
    acc.x = fmaf(v, g.x, acc.x); acc.y = fmaf(v, g.y, acc.y);
    acc.z = fmaf(v, g.z, acc.z); acc.w = fmaf(v, g.w, acc.w);
  }
  // relu (applies to both the a-half and b-half)
  acc.x = fmaxf(acc.x, 0.f); acc.y = fmaxf(acc.y, 0.f);
  acc.z = fmaxf(acc.z, 0.f); acc.w = fmaxf(acc.w, 0.f);

  // gate: T = sigmoid(dot(b, wg)); only b-half (lanes>=32) contributes
  float part = 0.f;
  if (lane >= 32) {
    float4 wgv = *(const float4*)(wg + sub * 4);
    part = acc.x * wgv.x + acc.y * wgv.y + acc.z * wgv.z + acc.w * wgv.w;
  }
#pragma unroll
  for (int off = 32; off > 0; off >>= 1) part += __shfl_xor(part, off);
  float T = 1.f / (1.f + __expf(-part));

  // bring b over to the a-half lanes, blend, store (lanes 0-31 write 512B)
  float4 other;
  other.x = __shfl_xor(acc.x, 32);
  other.y = __shfl_xor(acc.y, 32);
  other.z = __shfl_xor(acc.z, 32);
  other.w = __shfl_xor(acc.w, 32);
  if (lane < 32) {
    float u = 1.f - T;
    float4 yv;
    yv.x = T * acc.x + u * other.x;
    yv.y = T * acc.y + u * other.y;
    yv.z = T * acc.z + u * other.z;
    yv.w = T * acc.w + u * other.w;
    *(float4*)(y + (size_t)row * 128 + sub * 4) = yv;
  }
}

// ---------------- final spmm: out = A @ y ----------------------------------
// one wave per row; half-waves process even/odd edges (float4 gathers),
// combined via shfl_xor(32) at the end. Serial chain per row is halved.
__global__ __launch_bounds__(256) void k_spmm_out(const int* __restrict__ rp,
                                                  const int2* __restrict__ ccv,
                                                  const float* __restrict__ y,
                                                  float* __restrict__ out, int n) {
  int row = (int)((blockIdx.x * blockDim.x + threadIdx.x) >> 6);
  int lane = threadIdx.x & 63;
  if (row >= n) return;
  int s = rp[row], e = rp[row + 1];
  int h = lane >> 5, sub = lane & 31;
  const float* ysub = y + sub * 4;
  float4 o = {0.f, 0.f, 0.f, 0.f};

  int i = s + h;
  for (; i + 2 < e; i += 4) {  // this half handles i and i+2
    int2 m0 = ccv[i], m1 = ccv[i + 2];
    float4 g0 = *(const float4*)(ysub + (size_t)m0.x * 128);
    float4 g1 = *(const float4*)(ysub + (size_t)m1.x * 128);
    float v0 = __int_as_float(m0.y), v1 = __int_as_float(m1.y);
    o.x = fmaf(v0, g0.x, o.x); o.y = fmaf(v0, g0.y, o.y);
    o.z = fmaf(v0, g0.z, o.z); o.w = fmaf(v0, g0.w, o.w);
    o.x = fmaf(v1, g1.x, o.x); o.y = fmaf(v1, g1.y, o.y);
    o.z = fmaf(v1, g1.z, o.z); o.w = fmaf(v1, g1.w, o.w);
  }
  if (i < e) {
    int2 m = ccv[i];
    float4 g = *(const float4*)(ysub + (size_t)m.x * 128);
    float v = __int_as_float(m.y);
    o.x = fmaf(v, g.x, o.x); o.y = fmaf(v, g.y, o.y);
    o.z = fmaf(v, g.z, o.z); o.w = fmaf(v, g.w, o.w);
  }
  // combine even/odd halves
  o.x += __shfl_xor(o.x, 32);
  o.y += __shfl_xor(o.y, 32);
  o.z += __shfl_xor(o.z, 32);
  o.w += __shfl_xor(o.w, 32);
  if (lane < 32) {
    *(float4*)(out + (size_t)row * 128 + sub * 4) = o;
  }
}

// ---------------------------------------------------------------------------
extern "C" void kernel_launch(void* const* d_in, const int* in_sizes, int n_in,
                              void* d_out, int out_size, void* d_ws, size_t ws_size,
                              hipStream_t stream) {
  const float* X  = (const float*)d_in[0];
  const float* w1 = (const float*)d_in[1];
  const float* w2 = (const float*)d_in[2];
  const float* wg = (const float*)d_in[3];
  const float* Av = (const float*)d_in[4];
  const int*   Ar = (const int*)d_in[5];
  const int*   Ac = (const int*)d_in[6];
  float* out = (float*)d_out;
  int N   = in_sizes[0] / 128;
  int NNZ = in_sizes[4];

  char* p = (char*)d_ws;
  auto alloc = [&](size_t b) {
    char* r = p;
    p += (b + 255) & ~(size_t)255;
    return r;
  };
  int*   rp   = (int*)alloc((size_t)(N + 1) * 4);
  int*   cnt  = (int*)alloc((size_t)N * 4);
  int*   fill = (int*)alloc((size_t)N * 4);
  int*   bsum = (int*)alloc(4096);
  int*   boff = (int*)alloc(4096);
  int2*  ccv  = (int2*)alloc((size_t)NNZ * 8);
  float* xw   = (float*)alloc((size_t)N * 128 * 4);
  float* y    = (float*)alloc((size_t)N * 128 * 4);

  hipMemsetAsync(cnt, 0, (size_t)N * 4, stream);
  hipMemsetAsync(fill, 0, (size_t)N * 4, stream);

  int eb = (NNZ + 255) / 256;
  int sb = (N + 1023) / 1024;
  k_hist<<<eb, 256, 0, stream>>>(Ar, cnt, NNZ);
  k_scan_local<<<sb, 1024, 0, stream>>>(cnt, rp, bsum, N);
  k_scan_bsums<<<1, 1024, 0, stream>>>(bsum, boff, sb, rp, N);
  k_scan_add<<<sb, 1024, 0, stream>>>(rp, boff, N);
  k_scatter<<<eb, 256, 0, stream>>>(Ar, Ac, Av, rp, fill, ccv, NNZ);
  k_gemm<<<(N + GR - 1) / GR, 256, 0, stream>>>(X, w2, xw, N);
  int wb = (N + 3) / 4;  // one 64-lane wave per row, 4 rows per 256-thread block
  k_spmm_ab<<<wb, 256, 0, stream>>>(rp, ccv, w1, xw, wg, y, N);
  k_spmm_out<<<wb, 256, 0, stream>>>(rp, ccv, y, out, N);
}

// Round 3
// 452.142 us; speedup vs baseline: 1.5505x; 1.3227x over previous
//
#include <hip/hip_runtime.h>
#include <hip/hip_bf16.h>
#include <hip/hip_fp16.h>

// ---------------------------------------------------------------------------
// GCN-align highway:
//   xw = X @ w2                           (dense GEMM, f32 vector, f16 out)
//   a  = relu(A @ w1); b = relu(A @ xw)   (fused dual CSR spmm, f16 gathers)
//   T  = sigmoid(b @ wg); y = T*a + (1-T)*b  (fused into spmm epilogue)
//   out = A @ y                           (CSR spmm, f16 gathers, f32 out)
// w1 and xw are packed interleaved as f16: wx[c][0..127]=w1[c], [128..255]=xw[c]
// so ONE 512B wave-gather per edge serves both matrices. Accumulation is f32.
// ---------------------------------------------------------------------------

#define GR 64  // rows per GEMM block

// ---------------- histogram ----------------
__global__ void k_hist(const int* __restrict__ rows, int* __restrict__ cnt, int nnz) {
  int e = blockIdx.x * blockDim.x + threadIdx.x;
  if (e < nnz) atomicAdd(&cnt[rows[e]], 1);
}

// ---------------- block-wide inclusive scan helper (blockDim = 1024) -------
__device__ __forceinline__ int block_incl_scan(int v, int* wsum) {
  int tid = threadIdx.x, lane = tid & 63, wid = tid >> 6;
  int incl = v;
#pragma unroll
  for (int off = 1; off < 64; off <<= 1) {
    int t = __shfl_up(incl, off);
    if (lane >= off) incl += t;
  }
  if (lane == 63) wsum[wid] = incl;
  __syncthreads();
  if (wid == 0) {
    int nw = (int)(blockDim.x >> 6);
    int wv = (lane < nw) ? wsum[lane] : 0;
    int wi = wv;
#pragma unroll
    for (int off = 1; off < 16; off <<= 1) {
      int t = __shfl_up(wi, off);
      if (lane >= off) wi += t;
    }
    if (lane < nw) wsum[lane] = wi - wv;  // exclusive wave offsets
  }
  __syncthreads();
  return incl + wsum[wid];
}

__global__ __launch_bounds__(1024) void k_scan_local(const int* __restrict__ cnt,
                                                     int* __restrict__ rp,
                                                     int* __restrict__ bsum, int n) {
  __shared__ int wsum[16];
  int gid = blockIdx.x * 1024 + threadIdx.x;
  int v = (gid < n) ? cnt[gid] : 0;
  int incl = block_incl_scan(v, wsum);
  if (gid < n) rp[gid] = incl - v;          // block-local exclusive
  if (threadIdx.x == 1023) bsum[blockIdx.x] = incl;
}

__global__ __launch_bounds__(1024) void k_scan_bsums(int* __restrict__ bsum,
                                                     int* __restrict__ boff,
                                                     int nb, int* __restrict__ rp, int n) {
  __shared__ int wsum[16];
  int tid = threadIdx.x;
  int v = (tid < nb) ? bsum[tid] : 0;
  int incl = block_incl_scan(v, wsum);
  if (tid < nb) boff[tid] = incl - v;       // exclusive block offsets
  if (tid == nb - 1) rp[n] = incl;          // total == NNZ
}

__global__ __launch_bounds__(1024) void k_scan_add(int* __restrict__ rp,
                                                   const int* __restrict__ boff, int n) {
  int gid = blockIdx.x * 1024 + threadIdx.x;
  if (gid < n) rp[gid] += boff[blockIdx.x];
}

// ---------------- COO -> CSR scatter (packed {col,val} records) ------------
__global__ void k_scatter(const int* __restrict__ rows, const int* __restrict__ cols,
                          const float* __restrict__ vals, const int* __restrict__ rp,
                          int* __restrict__ fill, int2* __restrict__ ccv, int nnz) {
  int e = blockIdx.x * blockDim.x + threadIdx.x;
  if (e >= nnz) return;
  int r = rows[e];
  int p = rp[r] + atomicAdd(&fill[r], 1);
  int2 rec;
  rec.x = cols[e];
  rec.y = __float_as_int(vals[e]);
  ccv[p] = rec;
}

// ---------------- w1 f32 -> f16 into interleaved wx[.., 0..127] ------------
__global__ void k_w1cvt(const float* __restrict__ w1, __half* __restrict__ wx, int n) {
  int t = blockIdx.x * blockDim.x + threadIdx.x;  // one thread = 4 features
  if (t >= n * 32) return;
  int c = t >> 5, sub = t & 31;
  float4 f = *(const float4*)(w1 + (size_t)c * 128 + sub * 4);
  union { __half2 h2[2]; uint2 u; } u;
  u.h2[0] = __floats2half2_rn(f.x, f.y);
  u.h2[1] = __floats2half2_rn(f.z, f.w);
  *(uint2*)(wx + (size_t)c * 256 + sub * 4) = u.u;
}

// ---------------- dense GEMM: wx[..,128..255] = f16(X @ W) -----------------
__global__ __launch_bounds__(256) void k_gemm(const float* __restrict__ X,
                                              const float* __restrict__ W,
                                              __half* __restrict__ wx, int n) {
  __shared__ float ws[128 * 128];  // 64 KB: whole w2, [k][j]
  __shared__ float xs[GR * 128];   // 32 KB
  int tid = threadIdx.x;
  long row0 = (long)blockIdx.x * GR;
#pragma unroll
  for (int i = tid * 4; i < 128 * 128; i += 256 * 4)
    *(float4*)&ws[i] = *(const float4*)&W[i];
  for (int i = tid; i < GR * 32; i += 256) {
    int r = i >> 5, c = (i & 31) << 2;
    long rr = row0 + r;
    if (rr >= n) rr = n - 1;
    *(float4*)&xs[r * 128 + c] = *(const float4*)&X[rr * 128 + c];
  }
  __syncthreads();
  int cg = tid & 15, rg = tid >> 4;  // 16 col-groups x 16 row-groups
  int c0 = cg * 8;
  float acc[4][8];
#pragma unroll
  for (int i = 0; i < 4; ++i)
#pragma unroll
    for (int j = 0; j < 8; ++j) acc[i][j] = 0.f;

  for (int k = 0; k < 128; k += 4) {
    float4 xv[4];
#pragma unroll
    for (int i = 0; i < 4; ++i) xv[i] = *(float4*)&xs[(rg * 4 + i) * 128 + k];
#pragma unroll
    for (int kk = 0; kk < 4; ++kk) {
      float4 wa = *(float4*)&ws[(k + kk) * 128 + c0];
      float4 wb = *(float4*)&ws[(k + kk) * 128 + c0 + 4];
#pragma unroll
      for (int i = 0; i < 4; ++i) {
        float x = ((const float*)&xv[i])[kk];
        acc[i][0] = fmaf(x, wa.x, acc[i][0]);
        acc[i][1] = fmaf(x, wa.y, acc[i][1]);
        acc[i][2] = fmaf(x, wa.z, acc[i][2]);
        acc[i][3] = fmaf(x, wa.w, acc[i][3]);
        acc[i][4] = fmaf(x, wb.x, acc[i][4]);
        acc[i][5] = fmaf(x, wb.y, acc[i][5]);
        acc[i][6] = fmaf(x, wb.z, acc[i][6]);
        acc[i][7] = fmaf(x, wb.w, acc[i][7]);
      }
    }
  }
#pragma unroll
  for (int i = 0; i < 4; ++i) {
    long r = row0 + rg * 4 + i;
    if (r < n) {
      union { __half2 h2[4]; float4 f4; } u;
      u.h2[0] = __floats2half2_rn(acc[i][0], acc[i][1]);
      u.h2[1] = __floats2half2_rn(acc[i][2], acc[i][3]);
      u.h2[2] = __floats2half2_rn(acc[i][4], acc[i][5]);
      u.h2[3] = __floats2half2_rn(acc[i][6], acc[i][7]);
      *(float4*)(wx + r * 256 + 128 + c0) = u.f4;
    }
  }
}

// ---------------- fused dual spmm + relu + highway gate --------------------
// one wave per row. Lanes 0-31 take the w1 half of the wx row, lanes 32-63
// the xw half; ONE 8B load per lane per edge (wave: 512B = both matrices).
__global__ __launch_bounds__(256) void k_spmm_ab(const int* __restrict__ rp,
                                                 const int2* __restrict__ ccv,
                                                 const __half* __restrict__ wx,
                                                 const float* __restrict__ wg,
                                                 __half* __restrict__ y16, int n) {
  int row = (int)((blockIdx.x * blockDim.x + threadIdx.x) >> 6);
  int lane = threadIdx.x & 63;
  if (row >= n) return;
  int s = rp[row], e = rp[row + 1];
  int h = lane >> 5, sub = lane & 31;
  const __half* base = wx + h * 128 + sub * 4;  // 4 features per lane
  float ac0 = 0.f, ac1 = 0.f, ac2 = 0.f, ac3 = 0.f;

#define AB_EDGE(m)                                                     \
  {                                                                    \
    uint2 u = *(const uint2*)(base + (size_t)(m).x * 256);             \
    float v = __int_as_float((m).y);                                   \
    float2 f0 = __half22float2(*(__half2*)&u.x);                       \
    float2 f1 = __half22float2(*(__half2*)&u.y);                       \
    ac0 = fmaf(v, f0.x, ac0); ac1 = fmaf(v, f0.y, ac1);                \
    ac2 = fmaf(v, f1.x, ac2); ac3 = fmaf(v, f1.y, ac3);                \
  }

  int i = s;
  for (; i + 3 < e; i += 4) {
    int2 m0 = ccv[i], m1 = ccv[i + 1], m2 = ccv[i + 2], m3 = ccv[i + 3];
    AB_EDGE(m0) AB_EDGE(m1) AB_EDGE(m2) AB_EDGE(m3)
  }
  for (; i < e; ++i) {
    int2 m = ccv[i];
    AB_EDGE(m)
  }
#undef AB_EDGE

  // relu (both halves)
  ac0 = fmaxf(ac0, 0.f); ac1 = fmaxf(ac1, 0.f);
  ac2 = fmaxf(ac2, 0.f); ac3 = fmaxf(ac3, 0.f);

  // gate: T = sigmoid(dot(b, wg)); only xw-half (lanes>=32) contributes
  float part = 0.f;
  if (h) {
    float4 wgv = *(const float4*)(wg + sub * 4);
    part = ac0 * wgv.x + ac1 * wgv.y + ac2 * wgv.z + ac3 * wgv.w;
  }
#pragma unroll
  for (int off = 32; off > 0; off >>= 1) part += __shfl_xor(part, off);
  float T = 1.f / (1.f + __expf(-part));

  // bring b over to the a-half lanes, blend, store f16 (lanes 0-31: 256B row)
  float o0 = __shfl_xor(ac0, 32), o1 = __shfl_xor(ac1, 32);
  float o2 = __shfl_xor(ac2, 32), o3 = __shfl_xor(ac3, 32);
  if (!h) {
    float u = 1.f - T;
    union { __half2 h2[2]; uint2 u2; } st;
    st.h2[0] = __floats2half2_rn(T * ac0 + u * o0, T * ac1 + u * o1);
    st.h2[1] = __floats2half2_rn(T * ac2 + u * o2, T * ac3 + u * o3);
    *(uint2*)(y16 + (size_t)row * 128 + sub * 4) = st.u2;
  }
}

// ---------------- final spmm: out = A @ y ----------------------------------
// one wave per row; half-waves process even/odd edges (8B f16 gathers),
// combined via shfl_xor(32). f32 accumulate, f32 output.
__global__ __launch_bounds__(256) void k_spmm_out(const int* __restrict__ rp,
                                                  const int2* __restrict__ ccv,
                                                  const __half* __restrict__ y16,
                                                  float* __restrict__ out, int n) {
  int row = (int)((blockIdx.x * blockDim.x + threadIdx.x) >> 6);
  int lane = threadIdx.x & 63;
  if (row >= n) return;
  int s = rp[row], e = rp[row + 1];
  int h = lane >> 5, sub = lane & 31;
  const __half* ysub = y16 + sub * 4;  // 4 features per lane
  float ac0 = 0.f, ac1 = 0.f, ac2 = 0.f, ac3 = 0.f;

#define OUT_EDGE(m)                                                    \
  {                                                                    \
    uint2 u = *(const uint2*)(ysub + (size_t)(m).x * 128);             \
    float v = __int_as_float((m).y);                                   \
    float2 f0 = __half22float2(*(__half2*)&u.x);                       \
    float2 f1 = __half22float2(*(__half2*)&u.y);                       \
    ac0 = fmaf(v, f0.x, ac0); ac1 = fmaf(v, f0.y, ac1);                \
    ac2 = fmaf(v, f1.x, ac2); ac3 = fmaf(v, f1.y, ac3);                \
  }

  int i = s + h;  // this half handles edges s+h, s+h+2, ...
  for (; i + 2 < e; i += 4) {
    int2 m0 = ccv[i], m1 = ccv[i + 2];
    OUT_EDGE(m0) OUT_EDGE(m1)
  }
  if (i < e) {
    int2 m = ccv[i];
    OUT_EDGE(m)
  }
#undef OUT_EDGE

  // combine even/odd halves
  ac0 += __shfl_xor(ac0, 32);
  ac1 += __shfl_xor(ac1, 32);
  ac2 += __shfl_xor(ac2, 32);
  ac3 += __shfl_xor(ac3, 32);
  if (!h) {
    float4 ov = {ac0, ac1, ac2, ac3};
    *(float4*)(out + (size_t)row * 128 + sub * 4) = ov;
  }
}

// ---------------------------------------------------------------------------
extern "C" void kernel_launch(void* const* d_in, const int* in_sizes, int n_in,
                              void* d_out, int out_size, void* d_ws, size_t ws_size,
                              hipStream_t stream) {
  const float* X  = (const float*)d_in[0];
  const float* w1 = (const float*)d_in[1];
  const float* w2 = (const float*)d_in[2];
  const float* wg = (const float*)d_in[3];
  const float* Av = (const float*)d_in[4];
  const int*   Ar = (const int*)d_in[5];
  const int*   Ac = (const int*)d_in[6];
  float* out = (float*)d_out;
  int N   = in_sizes[0] / 128;
  int NNZ = in_sizes[4];

  char* p = (char*)d_ws;
  auto alloc = [&](size_t b) {
    char* r = p;
    p += (b + 255) & ~(size_t)255;
    return r;
  };
  int*    rp   = (int*)alloc((size_t)(N + 1) * 4);
  int*    cnt  = (int*)alloc((size_t)N * 4);
  int*    fill = (int*)alloc((size_t)N * 4);
  int*    bsum = (int*)alloc(4096);
  int*    boff = (int*)alloc(4096);
  int2*   ccv  = (int2*)alloc((size_t)NNZ * 8);
  __half* wx   = (__half*)alloc((size_t)N * 256 * 2);  // interleaved w1|xw f16
  __half* y16  = (__half*)alloc((size_t)N * 128 * 2);

  hipMemsetAsync(cnt, 0, (size_t)N * 4, stream);
  hipMemsetAsync(fill, 0, (size_t)N * 4, stream);

  int eb = (NNZ + 255) / 256;
  int sb = (N + 1023) / 1024;
  k_hist<<<eb, 256, 0, stream>>>(Ar, cnt, NNZ);
  k_scan_local<<<sb, 1024, 0, stream>>>(cnt, rp, bsum, N);
  k_scan_bsums<<<1, 1024, 0, stream>>>(bsum, boff, sb, rp, N);
  k_scan_add<<<sb, 1024, 0, stream>>>(rp, boff, N);
  k_scatter<<<eb, 256, 0, stream>>>(Ar, Ac, Av, rp, fill, ccv, NNZ);
  k_w1cvt<<<(N * 32 + 255) / 256, 256, 0, stream>>>(w1, wx, N);
  k_gemm<<<(N + GR - 1) / GR, 256, 0, stream>>>(X, w2, wx, N);
  int wb = (N + 3) / 4;  // one 64-lane wave per row, 4 rows per 256-thread block
  k_spmm_ab<<<wb, 256, 0, stream>>>(rp, ccv, wx, wg, y16, N);
  k_spmm_out<<<wb, 256, 0, stream>>>(rp, ccv, y16, out, N);
}

// Round 4
// 381.509 us; speedup vs baseline: 1.8375x; 1.1851x over previous
//
#include <hip/hip_runtime.h>
#include <hip/hip_bf16.h>
#include <hip/hip_fp16.h>

// ---------------------------------------------------------------------------
// GCN-align highway:
//   xw = X @ w2                           (MFMA f16 GEMM, f32 accumulate)
//   a  = relu(A @ w1); b = relu(A @ xw)   (fused dual CSR spmm, f16 gathers)
//   T  = sigmoid(b @ wg); y = T*a + (1-T)*b  (fused into spmm epilogue)
//   out = A @ y                           (CSR spmm, f16 gathers, f32 out)
// w1 and xw are packed interleaved as f16: wx[c][0..127]=w1[c], [128..255]=xw[c]
// so ONE 512B wave-gather per edge serves both matrices. Accumulation is f32.
// w2 is pre-transposed/swizzled (T2 XOR) to f16 once; GEMM blocks stage it
// into LDS with a linear conflict-free copy and read B-frags swizzled.
// ---------------------------------------------------------------------------

using f16x8 = __attribute__((ext_vector_type(8))) _Float16;
using f32x4 = __attribute__((ext_vector_type(4))) float;

// ---------------- histogram ----------------
__global__ void k_hist(const int* __restrict__ rows, int* __restrict__ cnt, int nnz) {
  int e = blockIdx.x * blockDim.x + threadIdx.x;
  if (e < nnz) atomicAdd(&cnt[rows[e]], 1);
}

// ---------------- block-wide inclusive scan helper (blockDim = 1024) -------
__device__ __forceinline__ int block_incl_scan(int v, int* wsum) {
  int tid = threadIdx.x, lane = tid & 63, wid = tid >> 6;
  int incl = v;
#pragma unroll
  for (int off = 1; off < 64; off <<= 1) {
    int t = __shfl_up(incl, off);
    if (lane >= off) incl += t;
  }
  if (lane == 63) wsum[wid] = incl;
  __syncthreads();
  if (wid == 0) {
    int nw = (int)(blockDim.x >> 6);
    int wv = (lane < nw) ? wsum[lane] : 0;
    int wi = wv;
#pragma unroll
    for (int off = 1; off < 16; off <<= 1) {
      int t = __shfl_up(wi, off);
      if (lane >= off) wi += t;
    }
    if (lane < nw) wsum[lane] = wi - wv;  // exclusive wave offsets
  }
  __syncthreads();
  return incl + wsum[wid];
}

__global__ __launch_bounds__(1024) void k_scan_local(const int* __restrict__ cnt,
                                                     int* __restrict__ rp,
                                                     int* __restrict__ bsum, int n) {
  __shared__ int wsum[16];
  int gid = blockIdx.x * 1024 + threadIdx.x;
  int v = (gid < n) ? cnt[gid] : 0;
  int incl = block_incl_scan(v, wsum);
  if (gid < n) rp[gid] = incl - v;          // block-local exclusive
  if (threadIdx.x == 1023) bsum[blockIdx.x] = incl;
}

__global__ __launch_bounds__(1024) void k_scan_bsums(int* __restrict__ bsum,
                                                     int* __restrict__ boff,
                                                     int nb, int* __restrict__ rp, int n) {
  __shared__ int wsum[16];
  int tid = threadIdx.x;
  int v = (tid < nb) ? bsum[tid] : 0;
  int incl = block_incl_scan(v, wsum);
  if (tid < nb) boff[tid] = incl - v;       // exclusive block offsets
  if (tid == nb - 1) rp[n] = incl;          // total == NNZ
}

__global__ __launch_bounds__(1024) void k_scan_add(int* __restrict__ rp,
                                                   const int* __restrict__ boff, int n) {
  int gid = blockIdx.x * 1024 + threadIdx.x;
  if (gid < n) rp[gid] += boff[blockIdx.x];
}

// ---------------- COO -> CSR scatter (packed {col,val} records) ------------
__global__ void k_scatter(const int* __restrict__ rows, const int* __restrict__ cols,
                          const float* __restrict__ vals, const int* __restrict__ rp,
                          int* __restrict__ fill, int2* __restrict__ ccv, int nnz) {
  int e = blockIdx.x * blockDim.x + threadIdx.x;
  if (e >= nnz) return;
  int r = rows[e];
  int p = rp[r] + atomicAdd(&fill[r], 1);
  int2 rec;
  rec.x = cols[e];
  rec.y = __float_as_int(vals[e]);
  ccv[p] = rec;
}

// ---------------- w1 f32 -> f16 into interleaved wx[.., 0..127] ------------
__global__ void k_w1cvt(const float* __restrict__ w1, __half* __restrict__ wx, int n) {
  int t = blockIdx.x * blockDim.x + threadIdx.x;  // one thread = 4 features
  if (t >= n * 32) return;
  int c = t >> 5, sub = t & 31;
  float4 f = *(const float4*)(w1 + (size_t)c * 128 + sub * 4);
  union { __half2 h2[2]; uint2 u; } u;
  u.h2[0] = __floats2half2_rn(f.x, f.y);
  u.h2[1] = __floats2half2_rn(f.z, f.w);
  *(uint2*)(wx + (size_t)c * 256 + sub * 4) = u.u;
}

// ---------------- w2 f32 -> f16, transposed + T2-swizzled ------------------
// W2T byte(n, k..k+7) = n*256 + ((2k) ^ ((n&7)<<4)); element j at +2j.
__global__ void k_w2prep(const float* __restrict__ W, __half* __restrict__ W2T) {
  int t = blockIdx.x * blockDim.x + threadIdx.x;  // 2048 threads
  if (t >= 128 * 16) return;
  int n = t >> 4, kg = t & 15;
  union { _Float16 h[8]; uint4 u; } u;
#pragma unroll
  for (int j = 0; j < 8; ++j) u.h[j] = (_Float16)W[(kg * 8 + j) * 128 + n];
  int byte = n * 256 + ((kg * 16) ^ ((n & 7) << 4));
  *(uint4*)((char*)W2T + byte) = u.u;
}

// ---------------- MFMA GEMM: wx[..,128..255] = f16(X @ W) ------------------
// 256 threads = 4 waves; block does 256 rows, each wave 64 rows (4 m-tiles).
// mfma_f32_16x16x32_f16; A streamed f32->f16 from global; B from swizzled LDS.
#define BM 256
__global__ __launch_bounds__(256) void k_gemm(const float* __restrict__ X,
                                              const __half* __restrict__ W2T,
                                              __half* __restrict__ wx, int n) {
  __shared__ __half lds[16384];  // 32 KB swizzled W^T
  int tid = threadIdx.x;
#pragma unroll
  for (int it = 0; it < 8; ++it) {  // linear conflict-free copy
    int off = it * 4096 + tid * 16;
    *(uint4*)((char*)lds + off) = *(const uint4*)((const char*)W2T + off);
  }
  __syncthreads();

  int wid = tid >> 6, lane = tid & 63;
  int g = lane >> 4, lm = lane & 15;
  long rowbase = (long)blockIdx.x * BM + wid * 64;

  // A fragments: afr[m][kk], lane holds row (lm), k = kk*32 + g*8 + j
  f16x8 afr[4][4];
#pragma unroll
  for (int m = 0; m < 4; ++m) {
    long r = rowbase + m * 16 + lm;
    if (r >= n) r = n - 1;
    const float* xp = X + r * 128 + g * 8;
#pragma unroll
    for (int kk = 0; kk < 4; ++kk) {
      float4 lo = *(const float4*)(xp + kk * 32);
      float4 hi = *(const float4*)(xp + kk * 32 + 4);
      f16x8 a;
      a[0] = (_Float16)lo.x; a[1] = (_Float16)lo.y;
      a[2] = (_Float16)lo.z; a[3] = (_Float16)lo.w;
      a[4] = (_Float16)hi.x; a[5] = (_Float16)hi.y;
      a[6] = (_Float16)hi.z; a[7] = (_Float16)hi.w;
      afr[m][kk] = a;
    }
  }

#pragma unroll
  for (int nt = 0; nt < 8; ++nt) {
    int nn = nt * 16 + lm;
    int sw = (nn & 7) << 4;
    f16x8 bfr[4];
#pragma unroll
    for (int kk = 0; kk < 4; ++kk) {
      int byte = nn * 256 + ((kk * 64 + g * 16) ^ sw);
      bfr[kk] = *(f16x8*)((char*)lds + byte);
    }
#pragma unroll
    for (int m = 0; m < 4; ++m) {
      f32x4 acc = {0.f, 0.f, 0.f, 0.f};
#pragma unroll
      for (int kk = 0; kk < 4; ++kk)
        acc = __builtin_amdgcn_mfma_f32_16x16x32_f16(afr[m][kk], bfr[kk], acc, 0, 0, 0);
      // D: col = nn, row = rowbase + m*16 + g*4 + r  (scatter shorts; each
      // 16-lane group writes a contiguous 32B segment -> fully coalesced)
#pragma unroll
      for (int r = 0; r < 4; ++r) {
        long row = rowbase + m * 16 + g * 4 + r;
        if (row < n) wx[row * 256 + 128 + nn] = __float2half(acc[r]);
      }
    }
  }
}

// ---------------- fused dual spmm + relu + highway gate --------------------
// one wave per row. Lanes 0-31 take the w1 half of the wx row, lanes 32-63
// the xw half; ONE 8B load per lane per edge (wave: 512B = both matrices).
__global__ __launch_bounds__(256) void k_spmm_ab(const int* __restrict__ rp,
                                                 const int2* __restrict__ ccv,
                                                 const __half* __restrict__ wx,
                                                 const float* __restrict__ wg,
                                                 __half* __restrict__ y16, int n) {
  int row = (int)((blockIdx.x * blockDim.x + threadIdx.x) >> 6);
  int lane = threadIdx.x & 63;
  if (row >= n) return;
  int s = rp[row], e = rp[row + 1];
  int h = lane >> 5, sub = lane & 31;
  const __half* base = wx + h * 128 + sub * 4;  // 4 features per lane
  float ac0 = 0.f, ac1 = 0.f, ac2 = 0.f, ac3 = 0.f;

#define AB_EDGE(m)                                                     \
  {                                                                    \
    uint2 u = *(const uint2*)(base + (size_t)(m).x * 256);             \
    float v = __int_as_float((m).y);                                   \
    float2 f0 = __half22float2(*(__half2*)&u.x);                       \
    float2 f1 = __half22float2(*(__half2*)&u.y);                       \
    ac0 = fmaf(v, f0.x, ac0); ac1 = fmaf(v, f0.y, ac1);                \
    ac2 = fmaf(v, f1.x, ac2); ac3 = fmaf(v, f1.y, ac3);                \
  }

  int i = s;
  for (; i + 3 < e; i += 4) {
    int2 m0 = ccv[i], m1 = ccv[i + 1], m2 = ccv[i + 2], m3 = ccv[i + 3];
    AB_EDGE(m0) AB_EDGE(m1) AB_EDGE(m2) AB_EDGE(m3)
  }
  for (; i < e; ++i) {
    int2 m = ccv[i];
    AB_EDGE(m)
  }
#undef AB_EDGE

  // relu (both halves)
  ac0 = fmaxf(ac0, 0.f); ac1 = fmaxf(ac1, 0.f);
  ac2 = fmaxf(ac2, 0.f); ac3 = fmaxf(ac3, 0.f);

  // gate: T = sigmoid(dot(b, wg)); only xw-half (lanes>=32) contributes
  float part = 0.f;
  if (h) {
    float4 wgv = *(const float4*)(wg + sub * 4);
    part = ac0 * wgv.x + ac1 * wgv.y + ac2 * wgv.z + ac3 * wgv.w;
  }
#pragma unroll
  for (int off = 32; off > 0; off >>= 1) part += __shfl_xor(part, off);
  float T = 1.f / (1.f + __expf(-part));

  // bring b over to the a-half lanes, blend, store f16 (lanes 0-31: 256B row)
  float o0 = __shfl_xor(ac0, 32), o1 = __shfl_xor(ac1, 32);
  float o2 = __shfl_xor(ac2, 32), o3 = __shfl_xor(ac3, 32);
  if (!h) {
    float u = 1.f - T;
    union { __half2 h2[2]; uint2 u2; } st;
    st.h2[0] = __floats2half2_rn(T * ac0 + u * o0, T * ac1 + u * o1);
    st.h2[1] = __floats2half2_rn(T * ac2 + u * o2, T * ac3 + u * o3);
    *(uint2*)(y16 + (size_t)row * 128 + sub * 4) = st.u2;
  }
}

// ---------------- final spmm: out = A @ y ----------------------------------
// one wave per row; half-waves process even/odd edges (8B f16 gathers),
// combined via shfl_xor(32). f32 accumulate, f32 output.
__global__ __launch_bounds__(256) void k_spmm_out(const int* __restrict__ rp,
                                                  const int2* __restrict__ ccv,
                                                  const __half* __restrict__ y16,
                                                  float* __restrict__ out, int n) {
  int row = (int)((blockIdx.x * blockDim.x + threadIdx.x) >> 6);
  int lane = threadIdx.x & 63;
  if (row >= n) return;
  int s = rp[row], e = rp[row + 1];
  int h = lane >> 5, sub = lane & 31;
  const __half* ysub = y16 + sub * 4;  // 4 features per lane
  float ac0 = 0.f, ac1 = 0.f, ac2 = 0.f, ac3 = 0.f;

#define OUT_EDGE(m)                                                    \
  {                                                                    \
    uint2 u = *(const uint2*)(ysub + (size_t)(m).x * 128);             \
    float v = __int_as_float((m).y);                                   \
    float2 f0 = __half22float2(*(__half2*)&u.x);                       \
    float2 f1 = __half22float2(*(__half2*)&u.y);                       \
    ac0 = fmaf(v, f0.x, ac0); ac1 = fmaf(v, f0.y, ac1);                \
    ac2 = fmaf(v, f1.x, ac2); ac3 = fmaf(v, f1.y, ac3);                \
  }

  int i = s + h;  // this half handles edges s+h, s+h+2, ...
  for (; i + 2 < e; i += 4) {
    int2 m0 = ccv[i], m1 = ccv[i + 2];
    OUT_EDGE(m0) OUT_EDGE(m1)
  }
  if (i < e) {
    int2 m = ccv[i];
    OUT_EDGE(m)
  }
#undef OUT_EDGE

  // combine even/odd halves
  ac0 += __shfl_xor(ac0, 32);
  ac1 += __shfl_xor(ac1, 32);
  ac2 += __shfl_xor(ac2, 32);
  ac3 += __shfl_xor(ac3, 32);
  if (!h) {
    float4 ov = {ac0, ac1, ac2, ac3};
    *(float4*)(out + (size_t)row * 128 + sub * 4) = ov;
  }
}

// ---------------------------------------------------------------------------
extern "C" void kernel_launch(void* const* d_in, const int* in_sizes, int n_in,
                              void* d_out, int out_size, void* d_ws, size_t ws_size,
                              hipStream_t stream) {
  const float* X  = (const float*)d_in[0];
  const float* w1 = (const float*)d_in[1];
  const float* w2 = (const float*)d_in[2];
  const float* wg = (const float*)d_in[3];
  const float* Av = (const float*)d_in[4];
  const int*   Ar = (const int*)d_in[5];
  const int*   Ac = (const int*)d_in[6];
  float* out = (float*)d_out;
  int N   = in_sizes[0] / 128;
  int NNZ = in_sizes[4];

  char* p = (char*)d_ws;
  auto alloc = [&](size_t b) {
    char* r = p;
    p += (b + 255) & ~(size_t)255;
    return r;
  };
  int*    rp   = (int*)alloc((size_t)(N + 1) * 4);
  int*    cnt  = (int*)alloc((size_t)N * 4);
  int*    fill = (int*)alloc((size_t)N * 4);
  int*    bsum = (int*)alloc(4096);
  int*    boff = (int*)alloc(4096);
  int2*   ccv  = (int2*)alloc((size_t)NNZ * 8);
  __half* wx   = (__half*)alloc((size_t)N * 256 * 2);  // interleaved w1|xw f16
  __half* y16  = (__half*)alloc((size_t)N * 128 * 2);
  __half* w2t  = (__half*)alloc(128 * 128 * 2);        // swizzled W^T f16

  hipMemsetAsync(cnt, 0, (size_t)N * 4, stream);
  hipMemsetAsync(fill, 0, (size_t)N * 4, stream);

  int eb = (NNZ + 255) / 256;
  int sb = (N + 1023) / 1024;
  k_hist<<<eb, 256, 0, stream>>>(Ar, cnt, NNZ);
  k_scan_local<<<sb, 1024, 0, stream>>>(cnt, rp, bsum, N);
  k_scan_bsums<<<1, 1024, 0, stream>>>(bsum, boff, sb, rp, N);
  k_scan_add<<<sb, 1024, 0, stream>>>(rp, boff, N);
  k_scatter<<<eb, 256, 0, stream>>>(Ar, Ac, Av, rp, fill, ccv, NNZ);
  k_w1cvt<<<(N * 32 + 255) / 256, 256, 0, stream>>>(w1, wx, N);
  k_w2prep<<<8, 256, 0, stream>>>(w2, w2t);
  k_gemm<<<(N + BM - 1) / BM, 256, 0, stream>>>(X, w2t, wx, N);
  int wb = (N + 3) / 4;  // one 64-lane wave per row, 4 rows per 256-thread block
  k_spmm_ab<<<wb, 256, 0, stream>>>(rp, ccv, wx, wg, y16, N);
  k_spmm_out<<<wb, 256, 0, stream>>>(rp, ccv, y16, out, N);
}

// Round 5
// 328.720 us; speedup vs baseline: 2.1326x; 1.1606x over previous
//
#include <hip/hip_runtime.h>
#include <hip/hip_bf16.h>
#include <hip/hip_fp16.h>

// ---------------------------------------------------------------------------
// GCN-align highway:
//   xw = X @ w2                           (MFMA f16 GEMM, f32 accumulate)
//   a  = relu(A @ w1); b = relu(A @ xw)   (fused dual CSR spmm, f16 gathers)
//   T  = sigmoid(b @ wg); y = T*a + (1-T)*b  (fused into spmm epilogue)
//   out = A @ y                           (CSR spmm, f16 gathers, f32 out)
// w1 and xw are packed interleaved as f16: wx[c][0..127]=w1[c], [128..255]=xw[c]
// so ONE 512B wave-gather per edge serves both matrices. Accumulation is f32.
// Edge loops use scalar-broadcast metadata: lane l preloads ccv[s+l], per-edge
// {col,val} goes to SGPRs via readlane -> gathers pipeline deeply.
// ---------------------------------------------------------------------------

using f16x8 = __attribute__((ext_vector_type(8))) _Float16;
using f32x4 = __attribute__((ext_vector_type(4))) float;

// ---------------- histogram (also emits per-edge rank within row) ----------
__global__ void k_hist(const int* __restrict__ rows, int* __restrict__ cnt,
                       int* __restrict__ rank, int nnz) {
  int e = blockIdx.x * blockDim.x + threadIdx.x;
  if (e < nnz) rank[e] = atomicAdd(&cnt[rows[e]], 1);
}

// ---------------- block-wide inclusive scan helper (blockDim = 1024) -------
__device__ __forceinline__ int block_incl_scan(int v, int* wsum) {
  int tid = threadIdx.x, lane = tid & 63, wid = tid >> 6;
  int incl = v;
#pragma unroll
  for (int off = 1; off < 64; off <<= 1) {
    int t = __shfl_up(incl, off);
    if (lane >= off) incl += t;
  }
  if (lane == 63) wsum[wid] = incl;
  __syncthreads();
  if (wid == 0) {
    int nw = (int)(blockDim.x >> 6);
    int wv = (lane < nw) ? wsum[lane] : 0;
    int wi = wv;
#pragma unroll
    for (int off = 1; off < 16; off <<= 1) {
      int t = __shfl_up(wi, off);
      if (lane >= off) wi += t;
    }
    if (lane < nw) wsum[lane] = wi - wv;  // exclusive wave offsets
  }
  __syncthreads();
  return incl + wsum[wid];
}

__global__ __launch_bounds__(1024) void k_scan_local(const int* __restrict__ cnt,
                                                     int* __restrict__ rp,
                                                     int* __restrict__ bsum, int n) {
  __shared__ int wsum[16];
  int gid = blockIdx.x * 1024 + threadIdx.x;
  int v = (gid < n) ? cnt[gid] : 0;
  int incl = block_incl_scan(v, wsum);
  if (gid < n) rp[gid] = incl - v;          // block-local exclusive
  if (threadIdx.x == 1023) bsum[blockIdx.x] = incl;
}

__global__ __launch_bounds__(1024) void k_scan_bsums(int* __restrict__ bsum,
                                                     int* __restrict__ boff,
                                                     int nb, int* __restrict__ rp, int n) {
  __shared__ int wsum[16];
  int tid = threadIdx.x;
  int v = (tid < nb) ? bsum[tid] : 0;
  int incl = block_incl_scan(v, wsum);
  if (tid < nb) boff[tid] = incl - v;       // exclusive block offsets
  if (tid == nb - 1) rp[n] = incl;          // total == NNZ
}

__global__ __launch_bounds__(1024) void k_scan_add(int* __restrict__ rp,
                                                   const int* __restrict__ boff, int n) {
  int gid = blockIdx.x * 1024 + threadIdx.x;
  if (gid < n) rp[gid] += boff[blockIdx.x];
}

// ---------------- COO -> CSR scatter (packed {col,val} records) ------------
__global__ void k_scatter(const int* __restrict__ rows, const int* __restrict__ cols,
                          const float* __restrict__ vals, const int* __restrict__ rp,
                          const int* __restrict__ rank, int2* __restrict__ ccv, int nnz) {
  int e = blockIdx.x * blockDim.x + threadIdx.x;
  if (e >= nnz) return;
  int p = rp[rows[e]] + rank[e];
  int2 rec;
  rec.x = cols[e];
  rec.y = __float_as_int(vals[e]);
  ccv[p] = rec;
}

// ---------------- w2 f32 -> f16, transposed + T2-swizzled ------------------
// W2T byte(n, k..k+7) = n*256 + ((2k) ^ ((n&7)<<4)); element j at +2j.
__global__ void k_w2prep(const float* __restrict__ W, __half* __restrict__ W2T) {
  int t = blockIdx.x * blockDim.x + threadIdx.x;  // 2048 threads
  if (t >= 128 * 16) return;
  int n = t >> 4, kg = t & 15;
  union { _Float16 h[8]; uint4 u; } u;
#pragma unroll
  for (int j = 0; j < 8; ++j) u.h[j] = (_Float16)W[(kg * 8 + j) * 128 + n];
  int byte = n * 256 + ((kg * 16) ^ ((n & 7) << 4));
  *(uint4*)((char*)W2T + byte) = u.u;
}

// ---------------- MFMA GEMM: wx[..,128..255] = f16(X @ W) ------------------
// 256 threads = 4 waves; block does 256 rows, each wave 64 rows (4 m-tiles).
// mfma_f32_16x16x32_f16; A streamed f32->f16 from global; B from swizzled LDS.
// Also converts this block's w1 rows -> wx[..,0..127] (fused former k_w1cvt).
#define BM 256
__global__ __launch_bounds__(256) void k_gemm(const float* __restrict__ X,
                                              const float* __restrict__ w1,
                                              const __half* __restrict__ W2T,
                                              __half* __restrict__ wx, int n) {
  __shared__ __half lds[16384];  // 32 KB swizzled W^T
  int tid = threadIdx.x;
#pragma unroll
  for (int it = 0; it < 8; ++it) {  // linear conflict-free copy
    int off = it * 4096 + tid * 16;
    *(uint4*)((char*)lds + off) = *(const uint4*)((const char*)W2T + off);
  }

  // fused w1 -> f16 conversion for this block's rows (independent of LDS)
  long r0 = (long)blockIdx.x * BM;
  for (int i = tid; i < BM * 16; i += 256) {
    int rr = i >> 4, gg = i & 15;
    long r = r0 + rr;
    if (r < n) {
      const float* src = w1 + r * 128 + gg * 8;
      float4 f0 = *(const float4*)src;
      float4 f1 = *(const float4*)(src + 4);
      union { __half2 h2[4]; uint4 u4; } cv;
      cv.h2[0] = __floats2half2_rn(f0.x, f0.y);
      cv.h2[1] = __floats2half2_rn(f0.z, f0.w);
      cv.h2[2] = __floats2half2_rn(f1.x, f1.y);
      cv.h2[3] = __floats2half2_rn(f1.z, f1.w);
      *(uint4*)(wx + r * 256 + gg * 8) = cv.u4;
    }
  }
  __syncthreads();

  int wid = tid >> 6, lane = tid & 63;
  int g = lane >> 4, lm = lane & 15;
  long rowbase = r0 + wid * 64;

  // A fragments: afr[m][kk], lane holds row (lm), k = kk*32 + g*8 + j
  f16x8 afr[4][4];
#pragma unroll
  for (int m = 0; m < 4; ++m) {
    long r = rowbase + m * 16 + lm;
    if (r >= n) r = n - 1;
    const float* xp = X + r * 128 + g * 8;
#pragma unroll
    for (int kk = 0; kk < 4; ++kk) {
      float4 lo = *(const float4*)(xp + kk * 32);
      float4 hi = *(const float4*)(xp + kk * 32 + 4);
      f16x8 a;
      a[0] = (_Float16)lo.x; a[1] = (_Float16)lo.y;
      a[2] = (_Float16)lo.z; a[3] = (_Float16)lo.w;
      a[4] = (_Float16)hi.x; a[5] = (_Float16)hi.y;
      a[6] = (_Float16)hi.z; a[7] = (_Float16)hi.w;
      afr[m][kk] = a;
    }
  }

#pragma unroll
  for (int nt = 0; nt < 8; ++nt) {
    int nn = nt * 16 + lm;
    int sw = (nn & 7) << 4;
    f16x8 bfr[4];
#pragma unroll
    for (int kk = 0; kk < 4; ++kk) {
      int byte = nn * 256 + ((kk * 64 + g * 16) ^ sw);
      bfr[kk] = *(f16x8*)((char*)lds + byte);
    }
#pragma unroll
    for (int m = 0; m < 4; ++m) {
      f32x4 acc = {0.f, 0.f, 0.f, 0.f};
#pragma unroll
      for (int kk = 0; kk < 4; ++kk)
        acc = __builtin_amdgcn_mfma_f32_16x16x32_f16(afr[m][kk], bfr[kk], acc, 0, 0, 0);
      // D: col = nn, row = rowbase + m*16 + g*4 + r  (scatter shorts; each
      // 16-lane group writes a contiguous 32B segment -> fully coalesced)
#pragma unroll
      for (int r = 0; r < 4; ++r) {
        long row = rowbase + m * 16 + g * 4 + r;
        if (row < n) wx[row * 256 + 128 + nn] = __float2half(acc[r]);
      }
    }
  }
}

// ---------------- fused dual spmm + relu + highway gate --------------------
// one wave per row. Lanes 0-31 take the w1 half of the wx row, lanes 32-63
// the xw half; ONE 8B load per lane per edge (wave: 512B = both matrices).
// Metadata: lane l preloads ccv[s+l]; per-edge readlane -> scalar col/val.
__global__ __launch_bounds__(256) void k_spmm_ab(const int* __restrict__ rp,
                                                 const int2* __restrict__ ccv,
                                                 const __half* __restrict__ wx,
                                                 const float* __restrict__ wg,
                                                 __half* __restrict__ y16, int n) {
  int row = (int)((blockIdx.x * blockDim.x + threadIdx.x) >> 6);
  int lane = threadIdx.x & 63;
  if (row >= n) return;
  int s = rp[row], e = rp[row + 1];
  int h = lane >> 5, sub = lane & 31;
  const __half* base = wx + h * 128 + sub * 4;  // 4 features per lane
  float ac0 = 0.f, ac1 = 0.f, ac2 = 0.f, ac3 = 0.f;

#define AB_EDGE(J)                                                       \
  {                                                                      \
    int col = __builtin_amdgcn_readlane(mc, (J));                        \
    float v = __int_as_float(__builtin_amdgcn_readlane(ml, (J)));        \
    uint2 u = *(const uint2*)(base + (size_t)col * 256);                 \
    float2 f0 = __half22float2(*(__half2*)&u.x);                         \
    float2 f1 = __half22float2(*(__half2*)&u.y);                         \
    ac0 = fmaf(v, f0.x, ac0); ac1 = fmaf(v, f0.y, ac1);                  \
    ac2 = fmaf(v, f1.x, ac2); ac3 = fmaf(v, f1.y, ac3);                  \
  }

  for (int chunk = s; chunk < e; chunk += 64) {
    int idx = chunk + lane;
    int2 m = (idx < e) ? ccv[idx] : make_int2(0, 0);
    int mc = m.x, ml = m.y;
    int cl = min(64, e - chunk);
    int j = 0;
    for (; j + 3 < cl; j += 4) {
      AB_EDGE(j) AB_EDGE(j + 1) AB_EDGE(j + 2) AB_EDGE(j + 3)
    }
    for (; j < cl; ++j) AB_EDGE(j)
  }
#undef AB_EDGE

  // relu (both halves)
  ac0 = fmaxf(ac0, 0.f); ac1 = fmaxf(ac1, 0.f);
  ac2 = fmaxf(ac2, 0.f); ac3 = fmaxf(ac3, 0.f);

  // gate: T = sigmoid(dot(b, wg)); only xw-half (lanes>=32) contributes
  float part = 0.f;
  if (h) {
    float4 wgv = *(const float4*)(wg + sub * 4);
    part = ac0 * wgv.x + ac1 * wgv.y + ac2 * wgv.z + ac3 * wgv.w;
  }
#pragma unroll
  for (int off = 32; off > 0; off >>= 1) part += __shfl_xor(part, off);
  float T = 1.f / (1.f + __expf(-part));

  // bring b over to the a-half lanes, blend, store f16 (lanes 0-31: 256B row)
  float o0 = __shfl_xor(ac0, 32), o1 = __shfl_xor(ac1, 32);
  float o2 = __shfl_xor(ac2, 32), o3 = __shfl_xor(ac3, 32);
  if (!h) {
    float u = 1.f - T;
    union { __half2 h2[2]; uint2 u2; } st;
    st.h2[0] = __floats2half2_rn(T * ac0 + u * o0, T * ac1 + u * o1);
    st.h2[1] = __floats2half2_rn(T * ac2 + u * o2, T * ac3 + u * o3);
    *(uint2*)(y16 + (size_t)row * 128 + sub * 4) = st.u2;
  }
}

// ---------------- final spmm: out = A @ y ----------------------------------
// one wave per row; full wave gathers one y16 row per edge (64 lanes x 4B),
// scalar-broadcast metadata. f32 accumulate, float2 stores.
__global__ __launch_bounds__(256) void k_spmm_out(const int* __restrict__ rp,
                                                  const int2* __restrict__ ccv,
                                                  const __half* __restrict__ y16,
                                                  float* __restrict__ out, int n) {
  int row = (int)((blockIdx.x * blockDim.x + threadIdx.x) >> 6);
  int lane = threadIdx.x & 63;
  if (row >= n) return;
  int s = rp[row], e = rp[row + 1];
  const __half* ysub = y16 + lane * 2;  // 2 features per lane
  float ac0 = 0.f, ac1 = 0.f;

#define OUT_EDGE(J)                                                      \
  {                                                                      \
    int col = __builtin_amdgcn_readlane(mc, (J));                        \
    float v = __int_as_float(__builtin_amdgcn_readlane(ml, (J)));        \
    float2 f = __half22float2(*(const __half2*)(ysub + (size_t)col * 128)); \
    ac0 = fmaf(v, f.x, ac0); ac1 = fmaf(v, f.y, ac1);                    \
  }

  for (int chunk = s; chunk < e; chunk += 64) {
    int idx = chunk + lane;
    int2 m = (idx < e) ? ccv[idx] : make_int2(0, 0);
    int mc = m.x, ml = m.y;
    int cl = min(64, e - chunk);
    int j = 0;
    for (; j + 3 < cl; j += 4) {
      OUT_EDGE(j) OUT_EDGE(j + 1) OUT_EDGE(j + 2) OUT_EDGE(j + 3)
    }
    for (; j < cl; ++j) OUT_EDGE(j)
  }
#undef OUT_EDGE

  float2 ov = {ac0, ac1};
  *(float2*)(out + (size_t)row * 128 + lane * 2) = ov;
}

// ---------------------------------------------------------------------------
extern "C" void kernel_launch(void* const* d_in, const int* in_sizes, int n_in,
                              void* d_out, int out_size, void* d_ws, size_t ws_size,
                              hipStream_t stream) {
  const float* X  = (const float*)d_in[0];
  const float* w1 = (const float*)d_in[1];
  const float* w2 = (const float*)d_in[2];
  const float* wg = (const float*)d_in[3];
  const float* Av = (const float*)d_in[4];
  const int*   Ar = (const int*)d_in[5];
  const int*   Ac = (const int*)d_in[6];
  float* out = (float*)d_out;
  int N   = in_sizes[0] / 128;
  int NNZ = in_sizes[4];

  char* p = (char*)d_ws;
  auto alloc = [&](size_t b) {
    char* r = p;
    p += (b + 255) & ~(size_t)255;
    return r;
  };
  int*    rp   = (int*)alloc((size_t)(N + 1) * 4);
  int*    cnt  = (int*)alloc((size_t)N * 4);
  int*    rank = (int*)alloc((size_t)NNZ * 4);
  int*    bsum = (int*)alloc(4096);
  int*    boff = (int*)alloc(4096);
  int2*   ccv  = (int2*)alloc((size_t)NNZ * 8);
  __half* wx   = (__half*)alloc((size_t)N * 256 * 2);  // interleaved w1|xw f16
  __half* y16  = (__half*)alloc((size_t)N * 128 * 2);
  __half* w2t  = (__half*)alloc(128 * 128 * 2);        // swizzled W^T f16

  hipMemsetAsync(cnt, 0, (size_t)N * 4, stream);

  int eb = (NNZ + 255) / 256;
  int sb = (N + 1023) / 1024;
  k_hist<<<eb, 256, 0, stream>>>(Ar, cnt, rank, NNZ);
  k_scan_local<<<sb, 1024, 0, stream>>>(cnt, rp, bsum, N);
  k_scan_bsums<<<1, 1024, 0, stream>>>(bsum, boff, sb, rp, N);
  k_scan_add<<<sb, 1024, 0, stream>>>(rp, boff, N);
  k_scatter<<<eb, 256, 0, stream>>>(Ar, Ac, Av, rp, rank, ccv, NNZ);
  k_w2prep<<<8, 256, 0, stream>>>(w2, w2t);
  k_gemm<<<(N + BM - 1) / BM, 256, 0, stream>>>(X, w1, w2t, wx, N);
  int wb = (N + 3) / 4;  // one 64-lane wave per row, 4 rows per 256-thread block
  k_spmm_ab<<<wb, 256, 0, stream>>>(rp, ccv, wx, wg, y16, N);
  k_spmm_out<<<wb, 256, 0, stream>>>(rp, ccv, y16, out, N);
}